// Round 7
// baseline (658.729 us; speedup 1.0000x reference)
//
#include <hip/hip_runtime.h>
#include <hip/hip_bf16.h>
#include <math.h>

#define B_TOTAL 262144
#define D 16
#define CTX 128
#define H 192
#define IN_DIM 145
#define KP1 160      // layer-1 K: [y(16), t(1), pad(15), h(128)]
#define M 32         // rows per block
#define BLOCK 256
#define NT (B_TOTAL / M)   // 8192 tiles
#define GRID_P 2048        // persistent blocks; 4 tiles each

typedef __attribute__((ext_vector_type(8))) short bf16x8;
typedef __attribute__((ext_vector_type(4))) float f32x4;
typedef __attribute__((ext_vector_type(4))) unsigned short u16x4;

// operand-swapped MFMA: computes Z^T = W^T * X^T with the SAME register
// fragments as Z = X*W. Thread owns 4 consecutive columns of one row.
#define MFMA(a, b, c) __builtin_amdgcn_mfma_f32_16x16x32_bf16((a), (b), (c), 0, 0, 0)

__device__ __forceinline__ unsigned short f2bf_rne(float f) {
    unsigned u = __builtin_bit_cast(unsigned, f);
    u += 0x7FFFu + ((u >> 16) & 1u);
    return (unsigned short)(u >> 16);
}
// truncation-based hi/lo split: hi = trunc-bf16(v), lo = RNE(v - hi)
__device__ __forceinline__ void split2(float v, unsigned short& hi, unsigned short& lo) {
    unsigned u = __builtin_bit_cast(unsigned, v);
    hi = (unsigned short)(u >> 16);
    float hf = __builtin_bit_cast(float, u & 0xFFFF0000u);
    lo = f2bf_rne(v - hf);
}
// phi = 0.5(1+erf(x/sqrt2)) via A&S 7.1.26 (|eps|<=1.5e-7), exp shared with pdf
__device__ __forceinline__ void gelu_pair(float x, float& a, float& gp) {
    float s   = x * x;
    float e   = __expf(-0.5f * s);                       // e^{-x^2/2}
    float az  = fabsf(x) * 0.70710678118654752f;
    float t   = __builtin_amdgcn_rcpf(fmaf(0.3275911f, az, 1.0f));
    float p   = t * (0.254829592f + t * (-0.284496736f + t * (1.421413741f +
                t * (-1.453152027f + t * 1.061405429f))));
    float erfv = __builtin_copysignf(1.0f - p * e, x);
    float phi  = fmaf(0.5f, erfv, 0.5f);
    gp = fmaf(0.39894228040143268f * x, e, phi);          // phi + x*pdf
    a  = x * phi;
}

// ---------- pre-kernel: weights -> [N][K] bf16 in d_ws ----------
// Wt1: [192][160] @0 (k' map: 0-15->y rows, 16->t row(144), 17-31->0, 32+i->h row 16+i)
// Wt2: [192][192] @30720 ; Wt3: [16][192] @67584
__global__ void prep_weights(const float* __restrict__ W1,
                             const float* __restrict__ W2,
                             const float* __restrict__ W3,
                             unsigned short* __restrict__ wt)
{
    int i = blockIdx.x * 256 + threadIdx.x;
    if (i < H * KP1) {
        int n = i / KP1, kp = i % KP1;
        float v = 0.0f;
        if (kp < 16)       v = W1[kp * H + n];
        else if (kp == 16) v = W1[144 * H + n];
        else if (kp >= 32) v = W1[(kp - 16) * H + n];
        wt[i] = f2bf_rne(v);
        return;
    }
    i -= H * KP1;
    if (i < H * H) {
        int n = i / H, k = i % H;
        wt[30720 + i] = f2bf_rne(W2[k * H + n]);
        return;
    }
    i -= H * H;
    if (i < D * H) {
        int n = i / H, k = i % H;
        wt[67584 + i] = f2bf_rne(W3[k * D + n]);
    }
}

// ---------- main kernel: persistent (4 tiles/block), NO register prefetch ----------
__global__ __launch_bounds__(BLOCK, 4) void odefunc_mfma(
    const float* __restrict__ t_ptr,
    const float* __restrict__ y,
    const float* __restrict__ h,
    const float* __restrict__ eps,
    const float* __restrict__ b1,
    const float* __restrict__ b2,
    const float* __restrict__ b3,
    const unsigned short* __restrict__ wt,
    float* __restrict__ out_f,
    float* __restrict__ out_dlogp,
    float* __restrict__ out_dh)
{
    // R5's aliased LDS layout (25600 B): staging {Xh,Xl,Th,Tl} aliases A/U.
    // Persistence adds one loop-bottom barrier (next-iter staging writes
    // alias A/U read by L3 of the current iter).
    __shared__ __align__(16) unsigned char smem[25600];
    unsigned short (*Xh)[168] = (unsigned short (*)[168])(smem);          // 10752 B
    unsigned short (*Xl)[40]  = (unsigned short (*)[40])(smem + 10752);   //  2560 B
    unsigned short (*Th)[40]  = (unsigned short (*)[40])(smem + 13312);   //  2560 B
    unsigned short (*Tl)[40]  = (unsigned short (*)[40])(smem + 15872);   //  2560 B
    unsigned short (*A)[200]  = (unsigned short (*)[200])(smem);          // 12800 B (alias)
    unsigned short (*U)[200]  = (unsigned short (*)[200])(smem + 12800);  // 12800 B (alias)

    const int tid  = threadIdx.x;
    const int lane = tid & 63;
    const int wv   = tid >> 6;
    const int quad = lane >> 4;
    const int l16  = lane & 15;

    const unsigned short* Wt1 = wt;
    const unsigned short* Wt2 = wt + 30720;
    const unsigned short* Wt3 = wt + 67584;

    // per-thread staging geometry (loop-invariant)
    const int task = tid >> 7, sidx = tid & 127;
    const int sr = sidx >> 2, sd4 = (sidx & 3) * 4;     // y/eps: row, col*4
    const float* ye_src = task ? eps : y;

    const f32x4 zf = {0.f, 0.f, 0.f, 0.f};

    for (int it = blockIdx.x; it < NT; it += GRID_P) {
        const size_t r0 = (size_t)it * M;

        // ------- zero dh slice (stores only; no dependence) -------
        {
            float4 z4 = {0.f, 0.f, 0.f, 0.f};
            #pragma unroll
            for (int i = 0; i < 4; ++i) {
                int idx = tid + i * BLOCK;            // 1024 float4 = 32 rows x 32
                int r = idx >> 5, c4 = (idx & 31) * 4;
                *(float4*)(out_dh + (r0 + r) * CTX + c4) = z4;
            }
        }

        // ------------- stage inputs (direct global -> LDS, as R5) -------------
        {   // y (hi/lo) and eps (hi/lo): 2 x 128 float4 tasks
            float4 v = *(const float4*)(ye_src + (r0 + sr) * D + sd4);
            ushort4 hi, lo;
            split2(v.x, hi.x, lo.x); split2(v.y, hi.y, lo.y);
            split2(v.z, hi.z, lo.z); split2(v.w, hi.w, lo.w);
            if (task == 0) { *(ushort4*)&Xh[sr][sd4] = hi; *(ushort4*)&Xl[sr][sd4] = lo; }
            else           { *(ushort4*)&Th[sr][sd4] = hi; *(ushort4*)&Tl[sr][sd4] = lo; }
        }
        if (tid < M) {      // t column + pads (cols 16..31); aliased by A/U, so per-iter
            int r = tid;
            float tv = t_ptr[0];
            unsigned short thi, tlo;
            split2(tv, thi, tlo);
            ushort4 z4 = {0, 0, 0, 0};
            ushort4 t4 = {thi, 0, 0, 0};
            ushort4 l4 = {tlo, 0, 0, 0};
            *(ushort4*)&Xh[r][16] = t4; *(ushort4*)&Xh[r][20] = z4;
            *(ushort4*)&Xh[r][24] = z4; *(ushort4*)&Xh[r][28] = z4;
            *(ushort4*)&Xl[r][16] = l4; *(ushort4*)&Xl[r][20] = z4;
            *(ushort4*)&Xl[r][24] = z4; *(ushort4*)&Xl[r][28] = z4;
            *(ushort4*)&Th[r][16] = z4; *(ushort4*)&Th[r][20] = z4;
            *(ushort4*)&Th[r][24] = z4; *(ushort4*)&Th[r][28] = z4;
            *(ushort4*)&Tl[r][16] = z4; *(ushort4*)&Tl[r][20] = z4;
            *(ushort4*)&Tl[r][24] = z4; *(ushort4*)&Tl[r][28] = z4;
        }
        #pragma unroll
        for (int i = 0; i < 4; ++i) {   // h: single bf16 plane, 1024 float4
            int idx = tid + i * BLOCK;
            int r = idx >> 5, c4 = (idx & 31) * 4;
            float4 v = *(const float4*)(h + (r0 + r) * CTX + c4);
            ushort4 hv = { f2bf_rne(v.x), f2bf_rne(v.y), f2bf_rne(v.z), f2bf_rne(v.w) };
            *(ushort4*)&Xh[r][32 + c4] = hv;
        }
        __syncthreads();   // B1: staging visible

        // ------------- layer 1 (operand-swapped: acc = Z^T tiles) -------------
        f32x4 z[2][3], u[2][3];
        #pragma unroll
        for (int rt = 0; rt < 2; ++rt)
            #pragma unroll
            for (int j = 0; j < 3; ++j) { z[rt][j] = zf; u[rt][j] = zf; }

        bf16x8 w1f[3][5];
        #pragma unroll
        for (int j = 0; j < 3; ++j) {
            int n = (wv * 3 + j) * 16 + l16;
            #pragma unroll
            for (int kc = 0; kc < 5; ++kc)
                w1f[j][kc] = *(const bf16x8*)(Wt1 + n * KP1 + kc * 32 + quad * 8);
        }
        #pragma unroll
        for (int kc = 0; kc < 5; ++kc)
            #pragma unroll
            for (int rt = 0; rt < 2; ++rt) {
                bf16x8 ah = *(const bf16x8*)&Xh[rt * 16 + l16][kc * 32 + quad * 8];
                #pragma unroll
                for (int j = 0; j < 3; ++j) z[rt][j] = MFMA(w1f[j][kc], ah, z[rt][j]);
            }
        #pragma unroll
        for (int rt = 0; rt < 2; ++rt) {   // chunk-0 lo + tangent hi/lo
            int m = rt * 16 + l16;
            bf16x8 al = *(const bf16x8*)&Xl[m][quad * 8];
            bf16x8 th = *(const bf16x8*)&Th[m][quad * 8];
            bf16x8 tl = *(const bf16x8*)&Tl[m][quad * 8];
            #pragma unroll
            for (int j = 0; j < 3; ++j) {
                z[rt][j] = MFMA(w1f[j][0], al, z[rt][j]);
                u[rt][j] = MFMA(w1f[j][0], th, u[rt][j]);
                u[rt][j] = MFMA(w1f[j][0], tl, u[rt][j]);
            }
        }
        // A/U alias the staging buffers: all waves' L1 LDS reads must complete
        // before epilogue-1 writes.
        __syncthreads();   // B2
        // epilogue 1: thread writes 4 consecutive columns -> ushort4 LDS stores
        #pragma unroll
        for (int j = 0; j < 3; ++j) {
            int n4 = (wv * 3 + j) * 16 + quad * 4;
            f32x4 bb4 = *(const f32x4*)(b1 + n4);
            #pragma unroll
            for (int rt = 0; rt < 2; ++rt) {
                int m = rt * 16 + l16;
                u16x4 a4, u4;
                #pragma unroll
                for (int rg = 0; rg < 4; ++rg) {
                    float x = z[rt][j][rg] + bb4[rg];
                    float a, gp; gelu_pair(x, a, gp);
                    a4[rg] = f2bf_rne(a);
                    u4[rg] = f2bf_rne(u[rt][j][rg] * gp);
                }
                *(u16x4*)&A[m][n4] = a4;
                *(u16x4*)&U[m][n4] = u4;
            }
        }
        __syncthreads();   // B3: A/U visible

        // ------------- layer 2 (operand-swapped) -------------
        f32x4 z2[2][3], u2[2][3];
        #pragma unroll
        for (int rt = 0; rt < 2; ++rt)
            #pragma unroll
            for (int j = 0; j < 3; ++j) { z2[rt][j] = zf; u2[rt][j] = zf; }

        bf16x8 w2f[3][6];
        #pragma unroll
        for (int j = 0; j < 3; ++j) {
            int n = (wv * 3 + j) * 16 + l16;
            #pragma unroll
            for (int kc = 0; kc < 6; ++kc)
                w2f[j][kc] = *(const bf16x8*)(Wt2 + n * H + kc * 32 + quad * 8);
        }
        #pragma unroll
        for (int kc = 0; kc < 6; ++kc)
            #pragma unroll
            for (int rt = 0; rt < 2; ++rt) {
                int m = rt * 16 + l16, o = kc * 32 + quad * 8;
                bf16x8 av = *(const bf16x8*)&A[m][o];
                bf16x8 uv = *(const bf16x8*)&U[m][o];
                #pragma unroll
                for (int j = 0; j < 3; ++j) {
                    z2[rt][j] = MFMA(w2f[j][kc], av, z2[rt][j]);
                    u2[rt][j] = MFMA(w2f[j][kc], uv, u2[rt][j]);
                }
            }
        __syncthreads();   // B4: all A/U reads done before overwrite
        #pragma unroll
        for (int j = 0; j < 3; ++j) {
            int n4 = (wv * 3 + j) * 16 + quad * 4;
            f32x4 bb4 = *(const f32x4*)(b2 + n4);
            #pragma unroll
            for (int rt = 0; rt < 2; ++rt) {
                int m = rt * 16 + l16;
                u16x4 a4, u4;
                #pragma unroll
                for (int rg = 0; rg < 4; ++rg) {
                    float x = z2[rt][j][rg] + bb4[rg];
                    float a, gp; gelu_pair(x, a, gp);
                    a4[rg] = f2bf_rne(a);
                    u4[rg] = f2bf_rne(u2[rt][j][rg] * gp);
                }
                *(u16x4*)&A[m][n4] = a4;
                *(u16x4*)&U[m][n4] = u4;
            }
        }
        __syncthreads();   // B5: epi2 A/U visible

        // ------------- layer 3 + outputs (operand-swapped) -------------
        // wave 0: rows 0-15 value | wave 1: rows 0-15 tangent | waves 2/3: rows 16-31
        {
            const int strm = wv & 1, r3 = wv >> 1;
            const unsigned short (*P)[200] = strm ? U : A;

            bf16x8 w3f[6];
            #pragma unroll
            for (int kc = 0; kc < 6; ++kc)
                w3f[kc] = *(const bf16x8*)(Wt3 + l16 * H + kc * 32 + quad * 8);

            f32x4 acc = zf;
            #pragma unroll
            for (int kc = 0; kc < 6; ++kc) {
                bf16x8 xv = *(const bf16x8*)&P[r3 * 16 + l16][kc * 32 + quad * 8];
                acc = MFMA(w3f[kc], xv, acc);
            }

            const int m = r3 * 16 + l16;
            if (strm == 0) {
                f32x4 bb4 = *(const f32x4*)(b3 + quad * 4);
                f32x4 o = acc + bb4;
                *(f32x4*)(out_f + (r0 + m) * D + quad * 4) = o;
            } else {
                f32x4 e4 = *(const f32x4*)(eps + (r0 + m) * D + quad * 4);
                float pr = acc[0] * e4[0] + acc[1] * e4[1] + acc[2] * e4[2] + acc[3] * e4[3];
                pr += __shfl_xor(pr, 16, 64);
                pr += __shfl_xor(pr, 32, 64);
                if (quad == 0)
                    out_dlogp[r0 + m] = -pr;
            }
        }
        __syncthreads();   // B6: L3's A/U reads done before next-iter staging (alias)
    }
}

extern "C" void kernel_launch(void* const* d_in, const int* in_sizes, int n_in,
                              void* d_out, int out_size, void* d_ws, size_t ws_size,
                              hipStream_t stream)
{
    const float* t   = (const float*)d_in[0];
    const float* y   = (const float*)d_in[1];
    const float* h   = (const float*)d_in[3];
    const float* eps = (const float*)d_in[4];
    const float* W1  = (const float*)d_in[5];
    const float* b1  = (const float*)d_in[6];
    const float* W2  = (const float*)d_in[7];
    const float* b2  = (const float*)d_in[8];
    const float* W3  = (const float*)d_in[9];
    const float* b3  = (const float*)d_in[10];

    float* out       = (float*)d_out;
    float* out_f     = out;
    float* out_dlogp = out + (size_t)B_TOTAL * D;
    float* out_dh    = out + (size_t)B_TOTAL * (D + 1);

    unsigned short* wt = (unsigned short*)d_ws;

    int prep_elems = H * KP1 + H * H + D * H;   // 70656
    prep_weights<<<(prep_elems + 255) / 256, 256, 0, stream>>>(W1, W2, W3, wt);

    odefunc_mfma<<<GRID_P, BLOCK, 0, stream>>>(
        t, y, h, eps, b1, b2, b3, wt, out_f, out_dlogp, out_dh);
}

// Round 8
// 478.107 us; speedup vs baseline: 1.3778x; 1.3778x over previous
//
#include <hip/hip_runtime.h>
#include <hip/hip_bf16.h>
#include <math.h>

#define B_TOTAL 262144
#define D 16
#define CTX 128
#define H 192
#define IN_DIM 145
#define KP1 160      // layer-1 K: [y(16), t(1), pad(15), h(128)]
#define M 32         // rows per block
#define BLOCK 512    // 8 waves: rw = wv>>2 (row-tile), cw = wv&3 (48-col group)

typedef __attribute__((ext_vector_type(8))) short bf16x8;
typedef __attribute__((ext_vector_type(4))) float f32x4;
typedef __attribute__((ext_vector_type(4))) unsigned short u16x4;

// operand-swapped MFMA: computes Z^T = W^T * X^T with the SAME register
// fragments as Z = X*W. Thread owns 4 consecutive columns of one row.
#define MFMA(a, b, c) __builtin_amdgcn_mfma_f32_16x16x32_bf16((a), (b), (c), 0, 0, 0)

__device__ __forceinline__ unsigned short f2bf_rne(float f) {
    unsigned u = __builtin_bit_cast(unsigned, f);
    u += 0x7FFFu + ((u >> 16) & 1u);
    return (unsigned short)(u >> 16);
}
// truncation-based hi/lo split: hi = trunc-bf16(v), lo = RNE(v - hi)
__device__ __forceinline__ void split2(float v, unsigned short& hi, unsigned short& lo) {
    unsigned u = __builtin_bit_cast(unsigned, v);
    hi = (unsigned short)(u >> 16);
    float hf = __builtin_bit_cast(float, u & 0xFFFF0000u);
    lo = f2bf_rne(v - hf);
}
// phi = 0.5(1+erf(x/sqrt2)) via A&S 7.1.26 (|eps|<=1.5e-7), exp shared with pdf
__device__ __forceinline__ void gelu_pair(float x, float& a, float& gp) {
    float s   = x * x;
    float e   = __expf(-0.5f * s);                       // e^{-x^2/2}
    float az  = fabsf(x) * 0.70710678118654752f;
    float t   = __builtin_amdgcn_rcpf(fmaf(0.3275911f, az, 1.0f));
    float p   = t * (0.254829592f + t * (-0.284496736f + t * (1.421413741f +
                t * (-1.453152027f + t * 1.061405429f))));
    float erfv = __builtin_copysignf(1.0f - p * e, x);
    float phi  = fmaf(0.5f, erfv, 0.5f);
    gp = fmaf(0.39894228040143268f * x, e, phi);          // phi + x*pdf
    a  = x * phi;
}

// ---------- pre-kernel: weights -> [N][K] bf16 in d_ws ----------
// Wt1: [192][160] @0 (k' map: 0-15->y rows, 16->t row(144), 17-31->0, 32+i->h row 16+i)
// Wt2: [192][192] @30720 ; Wt3: [16][192] @67584
__global__ void prep_weights(const float* __restrict__ W1,
                             const float* __restrict__ W2,
                             const float* __restrict__ W3,
                             unsigned short* __restrict__ wt)
{
    int i = blockIdx.x * 256 + threadIdx.x;
    if (i < H * KP1) {
        int n = i / KP1, kp = i % KP1;
        float v = 0.0f;
        if (kp < 16)       v = W1[kp * H + n];
        else if (kp == 16) v = W1[144 * H + n];
        else if (kp >= 32) v = W1[(kp - 16) * H + n];
        wt[i] = f2bf_rne(v);
        return;
    }
    i -= H * KP1;
    if (i < H * H) {
        int n = i / H, k = i % H;
        wt[30720 + i] = f2bf_rne(W2[k * H + n]);
        return;
    }
    i -= H * H;
    if (i < D * H) {
        int n = i / H, k = i % H;
        wt[67584 + i] = f2bf_rne(W3[k * D + n]);
    }
}

// ---------- main kernel: 8 waves per 32-row tile ----------
__global__ __launch_bounds__(BLOCK, 4) void odefunc_mfma(
    const float* __restrict__ t_ptr,
    const float* __restrict__ y,
    const float* __restrict__ h,
    const float* __restrict__ eps,
    const float* __restrict__ b1,
    const float* __restrict__ b2,
    const float* __restrict__ b3,
    const unsigned short* __restrict__ wt,
    float* __restrict__ out_f,
    float* __restrict__ out_dlogp,
    float* __restrict__ out_dh)
{
    // R5's aliased LDS layout (25600 B): staging {Xh,Xl,Th,Tl} aliases A/U.
    __shared__ __align__(16) unsigned char smem[25600];
    unsigned short (*Xh)[168] = (unsigned short (*)[168])(smem);          // 10752 B
    unsigned short (*Xl)[40]  = (unsigned short (*)[40])(smem + 10752);   //  2560 B
    unsigned short (*Th)[40]  = (unsigned short (*)[40])(smem + 13312);   //  2560 B
    unsigned short (*Tl)[40]  = (unsigned short (*)[40])(smem + 15872);   //  2560 B
    unsigned short (*A)[200]  = (unsigned short (*)[200])(smem);          // 12800 B (alias)
    unsigned short (*U)[200]  = (unsigned short (*)[200])(smem + 12800);  // 12800 B (alias)

    const int tid  = threadIdx.x;
    const int lane = tid & 63;
    const int wv   = tid >> 6;       // 0..7
    const int quad = lane >> 4;
    const int l16  = lane & 15;
    const int rw   = wv >> 2;        // row-tile 0/1 (rows rw*16 .. +15)
    const int cw   = wv & 3;         // column-group 0..3 (cols cw*48 .. +47)
    const size_t r0 = (size_t)blockIdx.x * M;

    const unsigned short* Wt1 = wt;
    const unsigned short* Wt2 = wt + 30720;
    const unsigned short* Wt3 = wt + 67584;

    // ------- zero dh slice (stores only; no dependence) -------
    {
        float4 z4 = {0.f, 0.f, 0.f, 0.f};
        #pragma unroll
        for (int i = 0; i < 2; ++i) {
            int idx = tid + i * BLOCK;            // 1024 float4 = 32 rows x 32
            int r = idx >> 5, c4 = (idx & 31) * 4;
            *(float4*)(out_dh + (r0 + r) * CTX + c4) = z4;
        }
    }

    // ------------- stage inputs -------------
    if (tid < 256) {   // y (hi/lo) and eps (hi/lo): 2 x 128 float4 tasks
        int task = tid >> 7, idx = tid & 127;
        int r = idx >> 2, d4 = (idx & 3) * 4;
        const float* src = task ? eps : y;
        float4 v = *(const float4*)(src + (r0 + r) * D + d4);
        ushort4 hi, lo;
        split2(v.x, hi.x, lo.x); split2(v.y, hi.y, lo.y);
        split2(v.z, hi.z, lo.z); split2(v.w, hi.w, lo.w);
        if (task == 0) { *(ushort4*)&Xh[r][d4] = hi; *(ushort4*)&Xl[r][d4] = lo; }
        else           { *(ushort4*)&Th[r][d4] = hi; *(ushort4*)&Tl[r][d4] = lo; }
    }
    if (tid < M) {      // t column + pads (cols 16..31)
        int r = tid;
        float tv = t_ptr[0];
        unsigned short thi, tlo;
        split2(tv, thi, tlo);
        ushort4 z4 = {0, 0, 0, 0};
        ushort4 t4 = {thi, 0, 0, 0};
        ushort4 l4 = {tlo, 0, 0, 0};
        *(ushort4*)&Xh[r][16] = t4; *(ushort4*)&Xh[r][20] = z4;
        *(ushort4*)&Xh[r][24] = z4; *(ushort4*)&Xh[r][28] = z4;
        *(ushort4*)&Xl[r][16] = l4; *(ushort4*)&Xl[r][20] = z4;
        *(ushort4*)&Xl[r][24] = z4; *(ushort4*)&Xl[r][28] = z4;
        *(ushort4*)&Th[r][16] = z4; *(ushort4*)&Th[r][20] = z4;
        *(ushort4*)&Th[r][24] = z4; *(ushort4*)&Th[r][28] = z4;
        *(ushort4*)&Tl[r][16] = z4; *(ushort4*)&Tl[r][20] = z4;
        *(ushort4*)&Tl[r][24] = z4; *(ushort4*)&Tl[r][28] = z4;
    }
    #pragma unroll
    for (int i = 0; i < 2; ++i) {   // h: single bf16 plane, 1024 float4
        int idx = tid + i * BLOCK;
        int r = idx >> 5, c4 = (idx & 31) * 4;
        float4 v = *(const float4*)(h + (r0 + r) * CTX + c4);
        ushort4 hv = { f2bf_rne(v.x), f2bf_rne(v.y), f2bf_rne(v.z), f2bf_rne(v.w) };
        *(ushort4*)&Xh[r][32 + c4] = hv;
    }
    __syncthreads();   // B1: staging visible

    const f32x4 zf = {0.f, 0.f, 0.f, 0.f};

    // ------------- layer 1 (operand-swapped; wave owns row-tile rw, cols cw*48..+47) ----
    f32x4 z[3], u[3];
    #pragma unroll
    for (int j = 0; j < 3; ++j) { z[j] = zf; u[j] = zf; }

    bf16x8 w1f[3][5];
    #pragma unroll
    for (int j = 0; j < 3; ++j) {
        int n = (cw * 3 + j) * 16 + l16;
        #pragma unroll
        for (int kc = 0; kc < 5; ++kc)
            w1f[j][kc] = *(const bf16x8*)(Wt1 + n * KP1 + kc * 32 + quad * 8);
    }
    #pragma unroll
    for (int kc = 0; kc < 5; ++kc) {
        bf16x8 ah = *(const bf16x8*)&Xh[rw * 16 + l16][kc * 32 + quad * 8];
        #pragma unroll
        for (int j = 0; j < 3; ++j) z[j] = MFMA(w1f[j][kc], ah, z[j]);
    }
    {   // chunk-0 lo + tangent hi/lo
        int m = rw * 16 + l16;
        bf16x8 al = *(const bf16x8*)&Xl[m][quad * 8];
        bf16x8 th = *(const bf16x8*)&Th[m][quad * 8];
        bf16x8 tl = *(const bf16x8*)&Tl[m][quad * 8];
        #pragma unroll
        for (int j = 0; j < 3; ++j) {
            z[j] = MFMA(w1f[j][0], al, z[j]);
            u[j] = MFMA(w1f[j][0], th, u[j]);
            u[j] = MFMA(w1f[j][0], tl, u[j]);
        }
    }
    // A/U alias the staging buffers: all waves' L1 LDS reads must complete
    // before epilogue-1 writes.
    __syncthreads();   // B2
    // epilogue 1: thread writes 4 consecutive columns -> ushort4 LDS stores
    #pragma unroll
    for (int j = 0; j < 3; ++j) {
        int n4 = (cw * 3 + j) * 16 + quad * 4;
        f32x4 bb4 = *(const f32x4*)(b1 + n4);
        int m = rw * 16 + l16;
        u16x4 a4, u4;
        #pragma unroll
        for (int rg = 0; rg < 4; ++rg) {
            float x = z[j][rg] + bb4[rg];
            float a, gp; gelu_pair(x, a, gp);
            a4[rg] = f2bf_rne(a);
            u4[rg] = f2bf_rne(u[j][rg] * gp);
        }
        *(u16x4*)&A[m][n4] = a4;
        *(u16x4*)&U[m][n4] = u4;
    }
    __syncthreads();   // B3: A/U visible

    // ------------- layer 2 (operand-swapped) -------------
    f32x4 z2[3], u2[3];
    #pragma unroll
    for (int j = 0; j < 3; ++j) { z2[j] = zf; u2[j] = zf; }

    bf16x8 w2f[3][6];
    #pragma unroll
    for (int j = 0; j < 3; ++j) {
        int n = (cw * 3 + j) * 16 + l16;
        #pragma unroll
        for (int kc = 0; kc < 6; ++kc)
            w2f[j][kc] = *(const bf16x8*)(Wt2 + n * H + kc * 32 + quad * 8);
    }
    #pragma unroll
    for (int kc = 0; kc < 6; ++kc) {
        int m = rw * 16 + l16, o = kc * 32 + quad * 8;
        bf16x8 av = *(const bf16x8*)&A[m][o];
        bf16x8 uv = *(const bf16x8*)&U[m][o];
        #pragma unroll
        for (int j = 0; j < 3; ++j) {
            z2[j] = MFMA(w2f[j][kc], av, z2[j]);
            u2[j] = MFMA(w2f[j][kc], uv, u2[j]);
        }
    }
    __syncthreads();   // B4: all A/U reads done before overwrite
    #pragma unroll
    for (int j = 0; j < 3; ++j) {
        int n4 = (cw * 3 + j) * 16 + quad * 4;
        f32x4 bb4 = *(const f32x4*)(b2 + n4);
        int m = rw * 16 + l16;
        u16x4 a4, u4;
        #pragma unroll
        for (int rg = 0; rg < 4; ++rg) {
            float x = z2[j][rg] + bb4[rg];
            float a, gp; gelu_pair(x, a, gp);
            a4[rg] = f2bf_rne(a);
            u4[rg] = f2bf_rne(u2[j][rg] * gp);
        }
        *(u16x4*)&A[m][n4] = a4;
        *(u16x4*)&U[m][n4] = u4;
    }
    __syncthreads();   // B5: epi2 A/U visible

    // ------------- layer 3 + outputs (operand-swapped; waves 0-3 only) -------------
    if (wv < 4) {
        const int strm = wv & 1, r3 = wv >> 1;
        const unsigned short (*P)[200] = strm ? U : A;

        bf16x8 w3f[6];
        #pragma unroll
        for (int kc = 0; kc < 6; ++kc)
            w3f[kc] = *(const bf16x8*)(Wt3 + l16 * H + kc * 32 + quad * 8);

        f32x4 acc = zf;
        #pragma unroll
        for (int kc = 0; kc < 6; ++kc) {
            bf16x8 xv = *(const bf16x8*)&P[r3 * 16 + l16][kc * 32 + quad * 8];
            acc = MFMA(w3f[kc], xv, acc);
        }

        const int m = r3 * 16 + l16;
        if (strm == 0) {
            f32x4 bb4 = *(const f32x4*)(b3 + quad * 4);
            f32x4 o = acc + bb4;
            *(f32x4*)(out_f + (r0 + m) * D + quad * 4) = o;
        } else {
            f32x4 e4 = *(const f32x4*)(eps + (r0 + m) * D + quad * 4);
            float pr = acc[0] * e4[0] + acc[1] * e4[1] + acc[2] * e4[2] + acc[3] * e4[3];
            pr += __shfl_xor(pr, 16, 64);
            pr += __shfl_xor(pr, 32, 64);
            if (quad == 0)
                out_dlogp[r0 + m] = -pr;
        }
    }
}

extern "C" void kernel_launch(void* const* d_in, const int* in_sizes, int n_in,
                              void* d_out, int out_size, void* d_ws, size_t ws_size,
                              hipStream_t stream)
{
    const float* t   = (const float*)d_in[0];
    const float* y   = (const float*)d_in[1];
    const float* h   = (const float*)d_in[3];
    const float* eps = (const float*)d_in[4];
    const float* W1  = (const float*)d_in[5];
    const float* b1  = (const float*)d_in[6];
    const float* W2  = (const float*)d_in[7];
    const float* b2  = (const float*)d_in[8];
    const float* W3  = (const float*)d_in[9];
    const float* b3  = (const float*)d_in[10];

    float* out       = (float*)d_out;
    float* out_f     = out;
    float* out_dlogp = out + (size_t)B_TOTAL * D;
    float* out_dh    = out + (size_t)B_TOTAL * (D + 1);

    unsigned short* wt = (unsigned short*)d_ws;

    int prep_elems = H * KP1 + H * H + D * H;   // 70656
    prep_weights<<<(prep_elems + 255) / 256, 256, 0, stream>>>(W1, W2, W3, wt);

    odefunc_mfma<<<B_TOTAL / M, BLOCK, 0, stream>>>(
        t, y, h, eps, b1, b2, b3, wt, out_f, out_dlogp, out_dh);
}

// Round 10
// 361.279 us; speedup vs baseline: 1.8233x; 1.3234x over previous
//
#include <hip/hip_runtime.h>
#include <hip/hip_bf16.h>
#include <math.h>

#define B_TOTAL 262144
#define D 16
#define CTX 128
#define H 192
#define IN_DIM 145
#define KP1 160      // layer-1 K: [y(16), t(1), pad(15), h(128)]
#define M 64         // rows per block; 4 waves, each covering all 64 rows x 48 cols
#define BLOCK 256

typedef __attribute__((ext_vector_type(8))) short bf16x8;
typedef __attribute__((ext_vector_type(4))) float f32x4;
typedef __attribute__((ext_vector_type(4))) unsigned short u16x4;

// operand-swapped MFMA: computes Z^T = W^T * X^T with the SAME register
// fragments as Z = X*W. Thread owns 4 consecutive columns of one row.
#define MFMA(a, b, c) __builtin_amdgcn_mfma_f32_16x16x32_bf16((a), (b), (c), 0, 0, 0)

__device__ __forceinline__ unsigned short f2bf_rne(float f) {
    unsigned u = __builtin_bit_cast(unsigned, f);
    u += 0x7FFFu + ((u >> 16) & 1u);
    return (unsigned short)(u >> 16);
}
// truncation-based hi/lo split: hi = trunc-bf16(v), lo = RNE(v - hi)
__device__ __forceinline__ void split2(float v, unsigned short& hi, unsigned short& lo) {
    unsigned u = __builtin_bit_cast(unsigned, v);
    hi = (unsigned short)(u >> 16);
    float hf = __builtin_bit_cast(float, u & 0xFFFF0000u);
    lo = f2bf_rne(v - hf);
}
// phi = 0.5(1+erf(x/sqrt2)) via A&S 7.1.26 (|eps|<=1.5e-7), exp shared with pdf
__device__ __forceinline__ void gelu_pair(float x, float& a, float& gp) {
    float s   = x * x;
    float e   = __expf(-0.5f * s);                       // e^{-x^2/2}
    float az  = fabsf(x) * 0.70710678118654752f;
    float t   = __builtin_amdgcn_rcpf(fmaf(0.3275911f, az, 1.0f));
    float p   = t * (0.254829592f + t * (-0.284496736f + t * (1.421413741f +
                t * (-1.453152027f + t * 1.061405429f))));
    float erfv = __builtin_copysignf(1.0f - p * e, x);
    float phi  = fmaf(0.5f, erfv, 0.5f);
    gp = fmaf(0.39894228040143268f * x, e, phi);          // phi + x*pdf
    a  = x * phi;
}

// ---------- pre-kernel: weights -> [N][K] bf16 in d_ws ----------
// Wt1: [192][160] @0 (k' map: 0-15->y rows, 16->t row(144), 17-31->0, 32+i->h row 16+i)
// Wt2: [192][192] @30720 ; Wt3: [16][192] @67584
__global__ void prep_weights(const float* __restrict__ W1,
                             const float* __restrict__ W2,
                             const float* __restrict__ W3,
                             unsigned short* __restrict__ wt)
{
    int i = blockIdx.x * 256 + threadIdx.x;
    if (i < H * KP1) {
        int n = i / KP1, kp = i % KP1;
        float v = 0.0f;
        if (kp < 16)       v = W1[kp * H + n];
        else if (kp == 16) v = W1[144 * H + n];
        else if (kp >= 32) v = W1[(kp - 16) * H + n];
        wt[i] = f2bf_rne(v);
        return;
    }
    i -= H * KP1;
    if (i < H * H) {
        int n = i / H, k = i % H;
        wt[30720 + i] = f2bf_rne(W2[k * H + n]);
        return;
    }
    i -= H * H;
    if (i < D * H) {
        int n = i / H, k = i % H;
        wt[67584 + i] = f2bf_rne(W3[k * D + n]);
    }
}

// ---------- main kernel: 4 waves, each with 12 independent acc chains ----------
__global__ __launch_bounds__(BLOCK, 3) void odefunc_mfma(
    const float* __restrict__ t_ptr,
    const float* __restrict__ y,
    const float* __restrict__ h,
    const float* __restrict__ eps,
    const float* __restrict__ b1,
    const float* __restrict__ b2,
    const float* __restrict__ b3,
    const unsigned short* __restrict__ wt,
    float* __restrict__ out_f,
    float* __restrict__ out_dlogp,
    float* __restrict__ out_dh)
{
    // Aliased LDS union for 64 rows: staging {Xh 21504 + Xl/Th/Tl 3x5120 = 36864}
    // dead after L1 reads; A/U {2 x 25600 = 51200} alias it. 51200 B -> 3 blk/CU.
    __shared__ __align__(16) unsigned char smem[51200];
    unsigned short (*Xh)[168] = (unsigned short (*)[168])(smem);          // 21504 B
    unsigned short (*Xl)[40]  = (unsigned short (*)[40])(smem + 21504);   //  5120 B
    unsigned short (*Th)[40]  = (unsigned short (*)[40])(smem + 26624);   //  5120 B
    unsigned short (*Tl)[40]  = (unsigned short (*)[40])(smem + 31744);   //  5120 B
    unsigned short (*A)[200]  = (unsigned short (*)[200])(smem);          // 25600 B (alias)
    unsigned short (*U)[200]  = (unsigned short (*)[200])(smem + 25600);  // 25600 B (alias)

    const int tid  = threadIdx.x;
    const int lane = tid & 63;
    const int wv   = tid >> 6;       // 0..3 (column-group; 48 cols each)
    const int quad = lane >> 4;
    const int l16  = lane & 15;
    const size_t r0 = (size_t)blockIdx.x * M;

    const unsigned short* Wt1 = wt;
    const unsigned short* Wt2 = wt + 30720;
    const unsigned short* Wt3 = wt + 67584;

    // ------- zero dh slice (stores only; no dependence) -------
    {
        float4 z4 = {0.f, 0.f, 0.f, 0.f};
        #pragma unroll
        for (int i = 0; i < 8; ++i) {
            int idx = tid + i * BLOCK;            // 2048 float4 = 64 rows x 32
            int r = idx >> 5, c4 = (idx & 31) * 4;
            *(float4*)(out_dh + (r0 + r) * CTX + c4) = z4;
        }
    }

    // ------------- stage inputs (straight-line, no computed branch) -------------
    {
        int r = tid >> 2, d4 = (tid & 3) * 4;     // 256 threads = 64 rows x 4 float4
        float4 vy = *(const float4*)(y   + (r0 + r) * D + d4);
        float4 ve = *(const float4*)(eps + (r0 + r) * D + d4);
        ushort4 hi, lo;
        split2(vy.x, hi.x, lo.x); split2(vy.y, hi.y, lo.y);
        split2(vy.z, hi.z, lo.z); split2(vy.w, hi.w, lo.w);
        *(ushort4*)&Xh[r][d4] = hi; *(ushort4*)&Xl[r][d4] = lo;
        split2(ve.x, hi.x, lo.x); split2(ve.y, hi.y, lo.y);
        split2(ve.z, hi.z, lo.z); split2(ve.w, hi.w, lo.w);
        *(ushort4*)&Th[r][d4] = hi; *(ushort4*)&Tl[r][d4] = lo;
    }
    if (tid < M) {      // t column + pads (cols 16..31)
        int r = tid;
        float tv = t_ptr[0];
        unsigned short thi, tlo;
        split2(tv, thi, tlo);
        ushort4 z4 = {0, 0, 0, 0};
        ushort4 t4 = {thi, 0, 0, 0};
        ushort4 l4 = {tlo, 0, 0, 0};
        *(ushort4*)&Xh[r][16] = t4; *(ushort4*)&Xh[r][20] = z4;
        *(ushort4*)&Xh[r][24] = z4; *(ushort4*)&Xh[r][28] = z4;
        *(ushort4*)&Xl[r][16] = l4; *(ushort4*)&Xl[r][20] = z4;
        *(ushort4*)&Xl[r][24] = z4; *(ushort4*)&Xl[r][28] = z4;
        *(ushort4*)&Th[r][16] = z4; *(ushort4*)&Th[r][20] = z4;
        *(ushort4*)&Th[r][24] = z4; *(ushort4*)&Th[r][28] = z4;
        *(ushort4*)&Tl[r][16] = z4; *(ushort4*)&Tl[r][20] = z4;
        *(ushort4*)&Tl[r][24] = z4; *(ushort4*)&Tl[r][28] = z4;
    }
    #pragma unroll
    for (int i = 0; i < 8; ++i) {   // h: single bf16 plane, 2048 float4
        int idx = tid + i * BLOCK;
        int r = idx >> 5, c4 = (idx & 31) * 4;
        float4 v = *(const float4*)(h + (r0 + r) * CTX + c4);
        ushort4 hv = { f2bf_rne(v.x), f2bf_rne(v.y), f2bf_rne(v.z), f2bf_rne(v.w) };
        *(ushort4*)&Xh[r][32 + c4] = hv;
    }
    __syncthreads();   // B1: staging visible

    const f32x4 zf = {0.f, 0.f, 0.f, 0.f};

    // ------------- layer 1 (operand-swapped; 12 independent acc chains) -------------
    // thread owns Z[m = rt*16+l16][n = (wv*3+j)*16 + quad*4 + rg]
    f32x4 z[4][3], u[4][3];
    #pragma unroll
    for (int rt = 0; rt < 4; ++rt)
        #pragma unroll
        for (int j = 0; j < 3; ++j) { z[rt][j] = zf; u[rt][j] = zf; }

    // weight fragments loaded INSIDE the kc loop: 12 VGPR transient, not 60 live
    #pragma unroll
    for (int kc = 0; kc < 5; ++kc) {
        bf16x8 w0 = *(const bf16x8*)(Wt1 + ((wv * 3 + 0) * 16 + l16) * KP1 + kc * 32 + quad * 8);
        bf16x8 w1 = *(const bf16x8*)(Wt1 + ((wv * 3 + 1) * 16 + l16) * KP1 + kc * 32 + quad * 8);
        bf16x8 w2 = *(const bf16x8*)(Wt1 + ((wv * 3 + 2) * 16 + l16) * KP1 + kc * 32 + quad * 8);
        #pragma unroll
        for (int rt = 0; rt < 4; ++rt) {
            bf16x8 ah = *(const bf16x8*)&Xh[rt * 16 + l16][kc * 32 + quad * 8];
            z[rt][0] = MFMA(w0, ah, z[rt][0]);
            z[rt][1] = MFMA(w1, ah, z[rt][1]);
            z[rt][2] = MFMA(w2, ah, z[rt][2]);
        }
    }
    {   // chunk-0 lo + tangent hi/lo (reload kc=0 fragments)
        bf16x8 w0 = *(const bf16x8*)(Wt1 + ((wv * 3 + 0) * 16 + l16) * KP1 + quad * 8);
        bf16x8 w1 = *(const bf16x8*)(Wt1 + ((wv * 3 + 1) * 16 + l16) * KP1 + quad * 8);
        bf16x8 w2 = *(const bf16x8*)(Wt1 + ((wv * 3 + 2) * 16 + l16) * KP1 + quad * 8);
        #pragma unroll
        for (int rt = 0; rt < 4; ++rt) {
            int m = rt * 16 + l16;
            bf16x8 al = *(const bf16x8*)&Xl[m][quad * 8];
            bf16x8 th = *(const bf16x8*)&Th[m][quad * 8];
            bf16x8 tl = *(const bf16x8*)&Tl[m][quad * 8];
            z[rt][0] = MFMA(w0, al, z[rt][0]);
            z[rt][1] = MFMA(w1, al, z[rt][1]);
            z[rt][2] = MFMA(w2, al, z[rt][2]);
            u[rt][0] = MFMA(w0, th, u[rt][0]);
            u[rt][1] = MFMA(w1, th, u[rt][1]);
            u[rt][2] = MFMA(w2, th, u[rt][2]);
            u[rt][0] = MFMA(w0, tl, u[rt][0]);
            u[rt][1] = MFMA(w1, tl, u[rt][1]);
            u[rt][2] = MFMA(w2, tl, u[rt][2]);
        }
    }
    // A/U alias the staging buffers: all waves' L1 LDS reads must complete
    // before epilogue-1 writes.
    __syncthreads();   // B2
    // epilogue 1: thread writes 4 consecutive columns -> ushort4 LDS stores
    #pragma unroll
    for (int j = 0; j < 3; ++j) {
        int n4 = (wv * 3 + j) * 16 + quad * 4;
        f32x4 bb4 = *(const f32x4*)(b1 + n4);
        #pragma unroll
        for (int rt = 0; rt < 4; ++rt) {
            int m = rt * 16 + l16;
            u16x4 a4, u4;
            #pragma unroll
            for (int rg = 0; rg < 4; ++rg) {
                float x = z[rt][j][rg] + bb4[rg];
                float a, gp; gelu_pair(x, a, gp);
                a4[rg] = f2bf_rne(a);
                u4[rg] = f2bf_rne(u[rt][j][rg] * gp);
            }
            *(u16x4*)&A[m][n4] = a4;
            *(u16x4*)&U[m][n4] = u4;
        }
    }
    __syncthreads();   // B3: A/U visible

    // ------------- layer 2 (operand-swapped; 24 acc chains) -------------
    f32x4 z2[4][3], u2[4][3];
    #pragma unroll
    for (int rt = 0; rt < 4; ++rt)
        #pragma unroll
        for (int j = 0; j < 3; ++j) { z2[rt][j] = zf; u2[rt][j] = zf; }

    #pragma unroll
    for (int kc = 0; kc < 6; ++kc) {
        bf16x8 w0 = *(const bf16x8*)(Wt2 + ((wv * 3 + 0) * 16 + l16) * H + kc * 32 + quad * 8);
        bf16x8 w1 = *(const bf16x8*)(Wt2 + ((wv * 3 + 1) * 16 + l16) * H + kc * 32 + quad * 8);
        bf16x8 w2 = *(const bf16x8*)(Wt2 + ((wv * 3 + 2) * 16 + l16) * H + kc * 32 + quad * 8);
        #pragma unroll
        for (int rt = 0; rt < 4; ++rt) {
            int m = rt * 16 + l16, o = kc * 32 + quad * 8;
            bf16x8 av = *(const bf16x8*)&A[m][o];
            bf16x8 uv = *(const bf16x8*)&U[m][o];
            z2[rt][0] = MFMA(w0, av, z2[rt][0]);
            z2[rt][1] = MFMA(w1, av, z2[rt][1]);
            z2[rt][2] = MFMA(w2, av, z2[rt][2]);
            u2[rt][0] = MFMA(w0, uv, u2[rt][0]);
            u2[rt][1] = MFMA(w1, uv, u2[rt][1]);
            u2[rt][2] = MFMA(w2, uv, u2[rt][2]);
        }
    }
    __syncthreads();   // B4: all A/U reads done before overwrite
    #pragma unroll
    for (int j = 0; j < 3; ++j) {
        int n4 = (wv * 3 + j) * 16 + quad * 4;
        f32x4 bb4 = *(const f32x4*)(b2 + n4);
        #pragma unroll
        for (int rt = 0; rt < 4; ++rt) {
            int m = rt * 16 + l16;
            u16x4 a4, u4;
            #pragma unroll
            for (int rg = 0; rg < 4; ++rg) {
                float x = z2[rt][j][rg] + bb4[rg];
                float a, gp; gelu_pair(x, a, gp);
                a4[rg] = f2bf_rne(a);
                u4[rg] = f2bf_rne(u2[rt][j][rg] * gp);
            }
            *(u16x4*)&A[m][n4] = a4;
            *(u16x4*)&U[m][n4] = u4;
        }
    }
    __syncthreads();   // B5: epi2 A/U visible

    // ------------- layer 3 + outputs (operand-swapped) -------------
    // wave: strm = wv&1 (value/tangent), row-tiles (wv>>1) and (wv>>1)+2
    {
        const int strm = wv & 1;
        const int r3a = wv >> 1, r3b = (wv >> 1) + 2;
        const unsigned short (*P)[200] = strm ? U : A;

        f32x4 acc_a = zf, acc_b = zf;
        #pragma unroll
        for (int kc = 0; kc < 6; ++kc) {
            bf16x8 wf = *(const bf16x8*)(Wt3 + l16 * H + kc * 32 + quad * 8);
            bf16x8 xa = *(const bf16x8*)&P[r3a * 16 + l16][kc * 32 + quad * 8];
            bf16x8 xb = *(const bf16x8*)&P[r3b * 16 + l16][kc * 32 + quad * 8];
            acc_a = MFMA(wf, xa, acc_a);
            acc_b = MFMA(wf, xb, acc_b);
        }

        const int ma = r3a * 16 + l16, mb = r3b * 16 + l16;
        if (strm == 0) {
            f32x4 bb4 = *(const f32x4*)(b3 + quad * 4);
            f32x4 oa = acc_a + bb4;
            f32x4 ob = acc_b + bb4;
            *(f32x4*)(out_f + (r0 + ma) * D + quad * 4) = oa;
            *(f32x4*)(out_f + (r0 + mb) * D + quad * 4) = ob;
        } else {
            f32x4 ea = *(const f32x4*)(eps + (r0 + ma) * D + quad * 4);
            f32x4 eb = *(const f32x4*)(eps + (r0 + mb) * D + quad * 4);
            float pa = acc_a[0] * ea[0] + acc_a[1] * ea[1] + acc_a[2] * ea[2] + acc_a[3] * ea[3];
            float pb = acc_b[0] * eb[0] + acc_b[1] * eb[1] + acc_b[2] * eb[2] + acc_b[3] * eb[3];
            pa += __shfl_xor(pa, 16, 64);
            pa += __shfl_xor(pa, 32, 64);
            pb += __shfl_xor(pb, 16, 64);
            pb += __shfl_xor(pb, 32, 64);
            if (quad == 0) {
                out_dlogp[r0 + ma] = -pa;
                out_dlogp[r0 + mb] = -pb;
            }
        }
    }
}

extern "C" void kernel_launch(void* const* d_in, const int* in_sizes, int n_in,
                              void* d_out, int out_size, void* d_ws, size_t ws_size,
                              hipStream_t stream)
{
    const float* t   = (const float*)d_in[0];
    const float* y   = (const float*)d_in[1];
    const float* h   = (const float*)d_in[3];
    const float* eps = (const float*)d_in[4];
    const float* W1  = (const float*)d_in[5];
    const float* b1  = (const float*)d_in[6];
    const float* W2  = (const float*)d_in[7];
    const float* b2  = (const float*)d_in[8];
    const float* W3  = (const float*)d_in[9];
    const float* b3  = (const float*)d_in[10];

    float* out       = (float*)d_out;
    float* out_f     = out;
    float* out_dlogp = out + (size_t)B_TOTAL * D;
    float* out_dh    = out + (size_t)B_TOTAL * (D + 1);

    unsigned short* wt = (unsigned short*)d_ws;

    int prep_elems = H * KP1 + H * H + D * H;   // 70656
    prep_weights<<<(prep_elems + 255) / 256, 256, 0, stream>>>(W1, W2, W3, wt);

    odefunc_mfma<<<B_TOTAL / M, BLOCK, 0, stream>>>(
        t, y, h, eps, b1, b2, b3, wt, out_f, out_dlogp, out_dh);
}